// Round 1
// baseline (921.371 us; speedup 1.0000x reference)
//
#include <hip/hip_runtime.h>
#include <math.h>
#include <stdint.h>

#define E_N 19
#define H_N 32
#define T_N 2048
#define B_N 64
#define G_N 128      // 4*H gate rows per chain
#define XCHUNK 64    // timesteps staged per LDS round
#define LOG2E 1.4426950408889634f

typedef _Float16 half2_t __attribute__((ext_vector_type(2)));
typedef int v2i_t __attribute__((ext_vector_type(2)));

__device__ __forceinline__ float sigm_rcp(float e) {  // 1/(1+e)
    return __builtin_amdgcn_rcpf(1.0f + e);
}

// One WAVE (one 64-thread block) per chain (b, e, dir). No barriers.
// Lane pairing: j = lane&31, half = lane>>5.
//   half0 lane j owns rows i_j (row j)    and g_j (row j+64): ig = i*g is LOCAL
//   half1 lane j owns rows f_j (row j+32) and o_j (row j+96): c,h update is LOCAL
// Cross-lane per step: ONE v_permlane32_swap (VALU, ~4cy — replaces the old
// ds_swizzle-based __shfl_xor and its mid-step lgkmcnt(0) drain).
// h broadcast via LDS: half1 ds_write_b16 h_j -> all lanes re-read 32 packed
// fp16 h as 4x ds_read_b128 (same-address broadcast, conflict-free).
__global__ __launch_bounds__(64)
__attribute__((amdgpu_waves_per_eu(3, 3)))
void lstm_chain_kernel(
    const float* __restrict__ x,     // [B, T, E]
    const float* __restrict__ w_ih,  // [E, 2, 4H]
    const float* __restrict__ w_hh,  // [E, 2, 4H, H]
    const float* __restrict__ b_ih,  // [E, 2, 4H]
    const float* __restrict__ b_hh,  // [E, 2, 4H]
    float* __restrict__ hT)          // [B, E, 2, H]
{
    const int lane  = threadIdx.x;
    const int chain = blockIdx.x;            // b*(E*2) + e*2 + d
    const int b  = chain / (E_N * 2);
    const int ed = chain - b * (E_N * 2);
    const int e  = ed >> 1;
    const int d  = ed & 1;
    const int j    = lane & 31;
    const int half = lane >> 5;

    const int r1 = j + 32 * half;        // i_j (half0) or f_j (half1) -> sigmoid
    const int r2 = j + 64 + 32 * half;   // g_j (half0, tanh) or o_j (half1, sigmoid)

    // ---- load fp32 weights, quantize to packed fp16 pairs (16+16 VGPRs) ----
    const float* wr1 = w_hh + ((size_t)ed * G_N + r1) * H_N;
    const float* wr2 = w_hh + ((size_t)ed * G_N + r2) * H_N;
    uint32_t w1p[16], w2p[16];
    #pragma unroll
    for (int m = 0; m < 16; ++m) {
        float2 v1 = ((const float2*)wr1)[m];
        float2 v2 = ((const float2*)wr2)[m];
        half2_t p1 = { (_Float16)v1.x, (_Float16)v1.y };
        half2_t p2 = { (_Float16)v2.x, (_Float16)v2.y };
        w1p[m] = __builtin_bit_cast(uint32_t, p1);
        w2p[m] = __builtin_bit_cast(uint32_t, p2);
    }

    const float wih1  = w_ih[(size_t)ed * G_N + r1];
    const float wih2  = w_ih[(size_t)ed * G_N + r2];
    const float bias1 = b_ih[(size_t)ed * G_N + r1] + b_hh[(size_t)ed * G_N + r1];
    const float bias2 = b_ih[(size_t)ed * G_N + r2] + b_hh[(size_t)ed * G_N + r2];

    // act2: half0 -> tanh(g) = 2*sigm(2g)-1 ; half1 -> sigmoid(o)
    const float K2 = half ? (-LOG2E) : (-2.0f * LOG2E);
    const float A2 = half ?  1.0f :  2.0f;
    const float B2 = half ?  0.0f : -1.0f;

    // LDS: h (32 fp16) + dummy write region (32 fp16) + x chunk (64 f32)
    __shared__ __align__(16) uint16_t hbuf[64];   // [0..31] real, [32..63] dummy
    __shared__ float xbuf[XCHUNK];

    if (lane < 32) hbuf[lane] = 0;      // zero real h slots
    float c = 0.0f;    // valid on half1
    float h = 0.0f;    // valid on half1

    const float* xbase = x + (size_t)b * T_N * E_N + e;
    // half1 writes real slot j, half0 writes dummy slot 32+j (branchless)
    const int hwr = j + 32 * (1 - half);

    // prefetch first x chunk into a register (consumed at loop head)
    {
        const int tt    = lane;
        const int tphys = d ? (T_N - 1 - tt) : tt;
        // first chunk load
        // (reg -> LDS at loop head; next chunk's global load issued right after,
        //  so its ~HBM latency hides under 64 steps of compute)
    }
    float xreg;
    {
        const int tphys0 = d ? (T_N - 1 - lane) : lane;
        xreg = xbase[(size_t)tphys0 * E_N];
    }

    for (int t0 = 0; t0 < T_N; t0 += XCHUNK) {
        // PIN: keep the 32 packed weight regs live across the inner loop (no-op).
        #pragma unroll
        for (int m = 0; m < 16; ++m) {
            asm volatile("" : "+v"(w1p[m]), "+v"(w2p[m]));
        }

        // stage this chunk (already in xreg), then issue next chunk's global load
        xbuf[lane] = xreg;
        if (t0 + XCHUNK < T_N) {
            const int tn    = t0 + XCHUNK + lane;
            const int tphys = d ? (T_N - 1 - tn) : tn;
            xreg = xbase[(size_t)tphys * E_N];
        }

        #pragma unroll 1
        for (int tl = 0; tl < XCHUNK; ++tl) {
            // broadcast reads: 32 h fp16 (4 x b128) + x (uniform b32)
            const uint4 q0 = ((const uint4*)hbuf)[0];   // units 0..7
            const uint4 q1 = ((const uint4*)hbuf)[1];   // units 8..15
            const uint4 q2 = ((const uint4*)hbuf)[2];   // units 16..23
            const uint4 q3 = ((const uint4*)hbuf)[3];   // units 24..31
            const float sx = xbuf[tl];

            uint32_t hp[16];
            hp[0]=q0.x; hp[1]=q0.y; hp[2]=q0.z; hp[3]=q0.w;
            hp[4]=q1.x; hp[5]=q1.y; hp[6]=q1.z; hp[7]=q1.w;
            hp[8]=q2.x; hp[9]=q2.y; hp[10]=q2.z; hp[11]=q2.w;
            hp[12]=q3.x; hp[13]=q3.y; hp[14]=q3.z; hp[15]=q3.w;

            // 4 independent 4-deep fdot2 chains per gate (was 2 x 8-deep):
            // halves the dependent-latency of the matvec.
            float a1  = fmaf(sx, wih1, bias1), a1b = 0.0f, a1c = 0.0f, a1d = 0.0f;
            float a2  = fmaf(sx, wih2, bias2), a2b = 0.0f, a2c = 0.0f, a2d = 0.0f;
            #pragma unroll
            for (int m = 0; m < 4; ++m) {
                a1  = __builtin_amdgcn_fdot2(__builtin_bit_cast(half2_t, hp[m]),
                                             __builtin_bit_cast(half2_t, w1p[m]),    a1,  false);
                a1b = __builtin_amdgcn_fdot2(__builtin_bit_cast(half2_t, hp[m+4]),
                                             __builtin_bit_cast(half2_t, w1p[m+4]),  a1b, false);
                a1c = __builtin_amdgcn_fdot2(__builtin_bit_cast(half2_t, hp[m+8]),
                                             __builtin_bit_cast(half2_t, w1p[m+8]),  a1c, false);
                a1d = __builtin_amdgcn_fdot2(__builtin_bit_cast(half2_t, hp[m+12]),
                                             __builtin_bit_cast(half2_t, w1p[m+12]), a1d, false);
                a2  = __builtin_amdgcn_fdot2(__builtin_bit_cast(half2_t, hp[m]),
                                             __builtin_bit_cast(half2_t, w2p[m]),    a2,  false);
                a2b = __builtin_amdgcn_fdot2(__builtin_bit_cast(half2_t, hp[m+4]),
                                             __builtin_bit_cast(half2_t, w2p[m+4]),  a2b, false);
                a2c = __builtin_amdgcn_fdot2(__builtin_bit_cast(half2_t, hp[m+8]),
                                             __builtin_bit_cast(half2_t, w2p[m+8]),  a2c, false);
                a2d = __builtin_amdgcn_fdot2(__builtin_bit_cast(half2_t, hp[m+12]),
                                             __builtin_bit_cast(half2_t, w2p[m+12]), a2d, false);
            }
            const float g1 = (a1 + a1b) + (a1c + a1d);
            const float g2 = (a2 + a2b) + (a2c + a2d);

            // act1: sigmoid on both halves (i_j / f_j)
            const float act1 = sigm_rcp(__builtin_amdgcn_exp2f(g1 * (-LOG2E)));
            // act2: tanh (half0: g_j) / sigmoid (half1: o_j)
            const float act2 = fmaf(A2, sigm_rcp(__builtin_amdgcn_exp2f(g2 * K2)), B2);

            const float ig  = act1 * act2;           // half0: i*g (valid); half1: f*o (junk)

            // lane j <-> lane j+32 exchange in VALU (replaces ds_swizzle shfl).
            // With both operands = ig, each lane's two outputs are {own, partner}
            // in some order regardless of the swap orientation, so
            // partner = r0 ^ r1 ^ own (exact, bitwise).
            const int igb = __builtin_bit_cast(int, ig);
            const v2i_t pr = __builtin_amdgcn_permlane32_swap(igb, igb, false, false);
            const float igx = __builtin_bit_cast(float, pr.x ^ pr.y ^ igb);

            // valid on half1 only (half0 computes garbage on same instructions)
            c = fmaf(act1, c, igx);                                   // f*c + i*g
            const float tc = fmaf(2.0f, sigm_rcp(
                __builtin_amdgcn_exp2f(c * (-2.0f * LOG2E))), -1.0f); // tanh(c)
            h = act2 * tc;                                            // o * tanh(c)

            // publish h: half1 -> real slot j; half0 -> dummy slot (branchless)
            hbuf[hwr] = __builtin_bit_cast(uint16_t, (_Float16)h);
        }
    }

    if (half) {
        hT[((size_t)(b * E_N + e) * 2 + d) * H_N + j] = h;
    }
}

// LayerNorm over 64 feats per (b,e), mean over e, FC -> out[b]. One wave per b.
__global__ __launch_bounds__(64) void head_kernel(
    const float* __restrict__ hT,      // [B, E, 64]
    const float* __restrict__ ln_gamma,// [E, 64]
    const float* __restrict__ ln_beta, // [E, 64]
    const float* __restrict__ fc_w,    // [64]
    const float* __restrict__ fc_b,    // [1]
    float* __restrict__ out)           // [B]
{
    const int b = blockIdx.x;
    const int f = threadIdx.x; // 0..63

    float acc = 0.0f;
    for (int e = 0; e < E_N; ++e) {
        const float v = hT[(size_t)(b * E_N + e) * 64 + f];
        float s = v, s2 = v * v;
        #pragma unroll
        for (int off = 32; off > 0; off >>= 1) {
            s  += __shfl_xor(s,  off);
            s2 += __shfl_xor(s2, off);
        }
        const float mean = s * (1.0f / 64.0f);
        const float var  = s2 * (1.0f / 64.0f) - mean * mean;
        const float inv  = rsqrtf(var + 1e-5f);
        acc += (v - mean) * inv * ln_gamma[e * 64 + f] + ln_beta[e * 64 + f];
    }
    float contrib = (acc * (1.0f / (float)E_N)) * fc_w[f];
    #pragma unroll
    for (int off = 32; off > 0; off >>= 1) contrib += __shfl_xor(contrib, off);
    if (f == 0) out[b] = contrib + fc_b[0];
}

extern "C" void kernel_launch(void* const* d_in, const int* in_sizes, int n_in,
                              void* d_out, int out_size, void* d_ws, size_t ws_size,
                              hipStream_t stream) {
    const float* x        = (const float*)d_in[0];
    const float* w_ih     = (const float*)d_in[1];
    const float* w_hh     = (const float*)d_in[2];
    const float* b_ih     = (const float*)d_in[3];
    const float* b_hh     = (const float*)d_in[4];
    const float* ln_gamma = (const float*)d_in[5];
    const float* ln_beta  = (const float*)d_in[6];
    const float* fc_w     = (const float*)d_in[7];
    const float* fc_b     = (const float*)d_in[8];
    float* out = (float*)d_out;
    float* hT  = (float*)d_ws;  // B*E*2*H floats

    lstm_chain_kernel<<<B_N * E_N * 2, 64, 0, stream>>>(x, w_ih, w_hh, b_ih, b_hh, hT);
    head_kernel<<<B_N, 64, 0, stream>>>(hT, ln_gamma, ln_beta, fc_w, fc_b, out);
}